// Round 4
// baseline (7663.277 us; speedup 1.0000x reference)
//
#include <hip/hip_runtime.h>

#define VV 50257
#define DD 50
#define TT 1024
#define BB 1024

__device__ __forceinline__ float rl(float v, int lane) {
    return __int_as_float(__builtin_amdgcn_readlane(__float_as_int(v), lane));
}
__device__ __forceinline__ float sigmf(float x) { return 1.0f / (1.0f + __expf(-x)); }
__device__ __forceinline__ float tanhf_fast(float x) {
    float e = __expf(-2.0f * fabsf(x));
    return copysignf((1.0f - e) / (1.0f + e), x);
}

// P1[v][j] = b1[0][j] + sum_d emb[v][d] * kx1[d][j]   (one-time, ~0.5 GFLOP)
__global__ void proj_emb(const float* __restrict__ emb, const float* __restrict__ kx1,
                         const float* __restrict__ b1, float* __restrict__ P1) {
    int j = threadIdx.x;             // 0..95
    int v0 = blockIdx.x * 8;
    #pragma unroll 1
    for (int vv = 0; vv < 8; ++vv) {
        int v = v0 + vv;
        if (v >= VV) return;
        float acc = b1[j];
        #pragma unroll
        for (int d = 0; d < DD; ++d)
            acc += emb[v * DD + d] * kx1[d * 96 + j];
        P1[v * 96 + j] = acc;
    }
}

// Block = 2 waves = 1 batch row, 1024 blocks (4 blocks/CU, 2 waves/SIMD).
// Overlaid 192-float register frame as SIX float[32] arrays (128 B each --
// small enough for promote-alloca; a single float[192] stays in scratch,
// measured R3: VGPR=128 + 68 MB scratch writes).
// Wave A (wv=0): kh2 -> Wa..Wf (z:Wa|Wb, r:Wc|Wd, h:We|Wf), h2 state, GRU2.
// Wave B (wv=1): kx2 z/r/h -> Wa/Wb/Wc, kh1 -> Wd/We, h1 state (lanes 0-31),
//                GRU1 gates, P1 prefetch; ships xt2 via one float4 LDS slot.
// ONE barrier per iter; slot ping-pong on t&1 replaces the second barrier.
__global__ __launch_bounds__(128, 2)
void rnn_seq(const int* __restrict__ tokens, const float* __restrict__ P1,
             const float* __restrict__ kh1, const float* __restrict__ b1,
             const float* __restrict__ kx2, const float* __restrict__ kh2,
             const float* __restrict__ b2, const float* __restrict__ wg,
             const float* __restrict__ bg, const float* __restrict__ wd,
             const float* __restrict__ bd, float* __restrict__ out) {
    const int lane = threadIdx.x & 63;
    const int wv   = threadIdx.x >> 6;
    const int row  = blockIdx.x;
    const int l32  = lane & 31;

    __shared__ float4 slot[2][64];

    float Wa[32], Wb[32], Wc[32], Wd[32], We[32], Wf[32];
    float bias0, bias1, bias2, bias3 = 0.f, bias4 = 0.f;

    if (wv == 0) {
        #pragma unroll
        for (int k = 0; k < 32; ++k) {
            Wa[k] = kh2[k * 192 + lane];                 // z, k 0..31
            Wb[k] = kh2[(32 + k) * 192 + lane];          // z, k 32..63
            Wc[k] = kh2[k * 192 + 64 + lane];            // r, k 0..31
            Wd[k] = kh2[(32 + k) * 192 + 64 + lane];     // r, k 32..63
            We[k] = kh2[k * 192 + 128 + lane];           // h, k 0..31
            Wf[k] = kh2[(32 + k) * 192 + 128 + lane];    // h, k 32..63
        }
        bias0 = b2[192 + lane];          // recurrent biases b2[1]
        bias1 = b2[256 + lane];
        bias2 = b2[320 + lane];
    } else {
        #pragma unroll
        for (int k = 0; k < 32; ++k) {
            Wa[k] = kx2[k * 192 + lane];                 // kx2 z
            Wb[k] = kx2[k * 192 + 64 + lane];            // kx2 r
            Wc[k] = kx2[k * 192 + 128 + lane];           // kx2 h
            Wd[k] = kh1[k * 96 + lane];                  // kh1 z|r cols
            We[k] = kh1[k * 96 + 64 + l32];              // kh1 h cols
            Wf[k] = 0.f;                                 // unused by wave B
        }
        bias0 = b2[lane];                // input biases b2[0]
        bias1 = b2[64 + lane];
        bias2 = b2[128 + lane];
        bias3 = b1[96 + lane];           // GRU1 recurrent biases b1[1]
        bias4 = b1[96 + 64 + l32];
    }

    float h = 0.f;           // wave A: h2[lane]; wave B: h1[lane] (lanes 0-31 valid)
    float pz = 0.f, ph = 0.f;
    int tokc = 0;
    const int tbase = row * TT;

    if (wv == 1) {
        int tok0 = tokens[tbase];
        int tok1 = tokens[tbase + 1];
        tokc = tokens[tbase + 2];
        // h1(0): recurrent pre-acts are biases only (h1(-1)=0)
        float pz0 = P1[tok0 * 96 + lane];
        float ph0 = P1[tok0 * 96 + 64 + l32];
        float tmp = bias3 + pz0;
        float rsh = __shfl_xor(tmp, 32);
        float z  = sigmf(tmp);
        float r  = sigmf(rsh);
        float hh = tanhf_fast(ph0 + r * bias4);
        h = (1.f - z) * hh;              // valid in lanes 0-31
        // p(1) in flight for iter 0's gate phase
        pz = P1[tok1 * 96 + lane];
        ph = P1[tok1 * 96 + 64 + l32];
    }
    __syncthreads();

    #pragma unroll 1
    for (int t = 0; t < TT; ++t) {
        float a0, a1, a2, a3 = 0.f, a4 = 0.f;
        if (wv == 0) {
            // hm2 = h2(t-1) @ kh2 + b2[1]
            a0 = bias0; a1 = bias1; a2 = bias2;
            #pragma unroll
            for (int k = 0; k < 32; ++k) {
                float s = rl(h, k);
                a0 += s * Wa[k];
                a1 += s * Wc[k];
                a2 += s * We[k];
            }
            #pragma unroll
            for (int k = 0; k < 32; ++k) {
                float s = rl(h, 32 + k);
                a0 += s * Wb[k];
                a1 += s * Wd[k];
                a2 += s * Wf[k];
            }
        } else {
            // xt2 = h1(t) @ kx2 + b2[0];  hm1 = h1(t) @ kh1 + b1[1]
            a0 = bias0; a1 = bias1; a2 = bias2; a3 = bias3; a4 = bias4;
            #pragma unroll
            for (int k = 0; k < 32; ++k) {
                float s = rl(h, k);
                a0 += s * Wa[k];
                a1 += s * Wb[k];
                a2 += s * Wc[k];
                a3 += s * Wd[k];
                a4 += s * We[k];
            }
            slot[t & 1][lane] = make_float4(a0, a1, a2, 0.f);
        }
        __syncthreads();
        if (wv == 0) {
            // GRU2 gates -> h2(t)   (reset applied after recurrent matmul)
            float4 p = slot[t & 1][lane];
            float z  = sigmf(p.x + a0);
            float r  = sigmf(p.y + a1);
            float hh = tanhf_fast(p.z + r * a2);
            h = z * h + (1.f - z) * hh;
        } else {
            // GRU1 gates -> h1(t+1)  (pz/ph = p(t+1))
            float tmp = a3 + pz;
            float rsh = __shfl_xor(tmp, 32);
            float z  = sigmf(tmp);
            float r  = sigmf(rsh);
            float hh = tanhf_fast(ph + r * a4);
            h = z * h + (1.f - z) * hh;
            // prefetch p(t+2); token for t+3
            pz = P1[tokc * 96 + lane];
            ph = P1[tokc * 96 + 64 + l32];
            int tn = t + 3; if (tn > TT - 1) tn = TT - 1;
            tokc = tokens[tbase + tn];
        }
    }

    // ---- tail: GLU + dense, wave A only (h = h2(T-1); no barriers here) ----
    if (wv == 0) {
        float g0 = bg[lane], g1 = bg[64 + lane], g2 = bg[128 + lane], g3 = bg[192 + lane];
        #pragma unroll 4
        for (int k = 0; k < 64; ++k) {
            float s = rl(h, k);
            const float* wr = wg + k * 256;
            g0 += s * wr[lane];
            g1 += s * wr[64 + lane];
            g2 += s * wr[128 + lane];
            g3 += s * wr[192 + lane];
        }
        float x0 = g0 * sigmf(g2);
        float x1 = g1 * sigmf(g3);
        float s = x0 * wd[lane] + x1 * wd[64 + lane];
        s += __shfl_xor(s, 32); s += __shfl_xor(s, 16); s += __shfl_xor(s, 8);
        s += __shfl_xor(s, 4);  s += __shfl_xor(s, 2);  s += __shfl_xor(s, 1);
        if (lane == 0) out[row] = sigmf(s + bd[0]);
    }
}

extern "C" void kernel_launch(void* const* d_in, const int* in_sizes, int n_in,
                              void* d_out, int out_size, void* d_ws, size_t ws_size,
                              hipStream_t stream) {
    const int*   tokens = (const int*)d_in[0];
    const float* emb = (const float*)d_in[1];
    const float* kx1 = (const float*)d_in[2];
    const float* kh1 = (const float*)d_in[3];
    const float* b1  = (const float*)d_in[4];
    const float* kx2 = (const float*)d_in[5];
    const float* kh2 = (const float*)d_in[6];
    const float* b2  = (const float*)d_in[7];
    const float* wg  = (const float*)d_in[8];
    const float* bg  = (const float*)d_in[9];
    const float* wd  = (const float*)d_in[10];
    const float* bd  = (const float*)d_in[11];
    float* out = (float*)d_out;
    float* P1  = (float*)d_ws;   // 50257*96*4 = 19.3 MB of workspace

    proj_emb<<<(VV + 7) / 8, 96, 0, stream>>>(emb, kx1, b1, P1);
    rnn_seq<<<BB, 128, 0, stream>>>(tokens, P1, kh1, b1, kx2, kh2, b2,
                                    wg, bg, wd, bd, out);
}